// Round 20
// baseline (362.406 us; speedup 1.0000x reference)
//
#include <hip/hip_runtime.h>

// GAT 3-layer, N=100000 nodes, E=1.6M edges (+N self loops), Fin=64, H=128.
// 9-dispatch pipeline:
//   setup{zero cur,g,done + convert W->Wt} -> K1{edge partition || gemm0}
//   -> p2{CSR build, 1024 thr} -> agg0 -> gemm1 -> agg1 -> gemm2 -> agg2
//   -> sum+finalize{vectorized, 2048 blocks, 64-slot replicated, ticket fused}.
// r20: readout was 44us @ 292GB/s (4B/lane loads, 1 block/CU). Now u16x8 loads
// (16B/lane, wave=4 rows/iter), 2048-block grid, 64-way g-slot replication.
// Aggregate stays EXACT r17 form (r18's guard caused scratch spills — branchless!).

#define NN 100000
#define NE 1600000
#define ET (NE + NN)   // edges + self loops
#define HD 128
#define NCB 98         // coarse buckets = ceil(NN / 1024)
#define CAP 18432      // bucket capacity (mean 16327, +16 sigma)
#define EB2 391        // edge-partition blocks = ceil(NE / 4096)
#define GB 782         // gemm blocks = ceil(NN / 128)
#define SB 2048        // sum blocks (8 per CU)
#define NSLOT 64       // replicated readout accumulator slots

typedef unsigned int uint;
typedef unsigned short ushort;
typedef unsigned char uchar;
typedef __attribute__((ext_vector_type(8))) short bf16x8;
typedef __attribute__((ext_vector_type(8))) ushort u16x8;
typedef __attribute__((ext_vector_type(4))) float f32x4;
typedef __attribute__((ext_vector_type(2))) float f32x2;

__device__ __forceinline__ ushort f2b(float f) {   // fp32 -> bf16 RTN-even
    uint u = __float_as_uint(f);
    return (ushort)((u + 0x7fffu + ((u >> 16) & 1u)) >> 16);
}
__device__ __forceinline__ float b2f(ushort v) { return __uint_as_float((uint)v << 16); }
__device__ __forceinline__ uchar f2fp8(float f) {  // fp32 -> fp8 e4m3 (OCP), RNE+sat
    return (uchar)(__builtin_amdgcn_cvt_pk_fp8_f32(f, f, 0, false) & 0xff);
}

// ---------------- setup: zero cur/g/done + convert W0/W1/W2 -> transposed bf16 Wt ----------------

__global__ __launch_bounds__(256) void setup_kernel(
        const float* __restrict__ W0, const float* __restrict__ W1,
        const float* __restrict__ W2, ushort* __restrict__ Wt0,
        ushort* __restrict__ Wt1, ushort* __restrict__ Wt2,
        int* __restrict__ cur, float* __restrict__ g, int* __restrict__ done) {
    const int i = blockIdx.x * 256 + threadIdx.x;   // 64 blocks -> i < 16384
    if (i < NCB * 16) cur[i] = 0;
    if (i < NSLOT * 128) g[i] = 0.f;
    if (i == 10000) *done = 0;
    if (i < 128 * 64) {                 // Wt0[n*64+k] = bf16(W0[k*128+n])
        int n = i >> 6, k = i & 63;
        Wt0[i] = f2b(W0[k * 128 + n]);
    }
    {                                   // Wt1/Wt2: i covers 128*128 exactly
        int n = i >> 7, k = i & 127;
        Wt1[i] = f2b(W1[k * 128 + n]);
        Wt2[i] = f2b(W2[k * 128 + n]);
    }
}

// ---------------- MFMA GEMM body: Hf8 = fp8(X @ W), fused fp32 alpha epilogue ----------------

template <int K, bool XF32>
__device__ __forceinline__ void gemm_body(int bid, const void* Xp,
                                          const ushort* __restrict__ Wt,
                                          const float* __restrict__ a_src,
                                          const float* __restrict__ a_dst,
                                          uchar* __restrict__ Hf8,
                                          float* __restrict__ As,
                                          float* __restrict__ Ad) {
    const int t = threadIdx.x;
    const int w = t >> 6;
    const int l = t & 63;
    const int c16 = l & 15;
    const int kg = l >> 4;
    const int rowBase = bid * 128 + w * 32;

    f32x4 acc[2][8] = {};

    const int r0c = min(rowBase + c16, NN - 1);
    const int r1c = min(rowBase + 16 + c16, NN - 1);

    #pragma unroll
    for (int ks = 0; ks < K / 32; ++ks) {
        const int k0 = ks * 32 + kg * 8;
        bf16x8 a0, a1;
        if (XF32) {
            const float* Xf = (const float*)Xp;
            float4 lo0 = *(const float4*)&Xf[(size_t)r0c * K + k0];
            float4 hi0 = *(const float4*)&Xf[(size_t)r0c * K + k0 + 4];
            float4 lo1 = *(const float4*)&Xf[(size_t)r1c * K + k0];
            float4 hi1 = *(const float4*)&Xf[(size_t)r1c * K + k0 + 4];
            a0[0] = (short)f2b(lo0.x); a0[1] = (short)f2b(lo0.y);
            a0[2] = (short)f2b(lo0.z); a0[3] = (short)f2b(lo0.w);
            a0[4] = (short)f2b(hi0.x); a0[5] = (short)f2b(hi0.y);
            a0[6] = (short)f2b(hi0.z); a0[7] = (short)f2b(hi0.w);
            a1[0] = (short)f2b(lo1.x); a1[1] = (short)f2b(lo1.y);
            a1[2] = (short)f2b(lo1.z); a1[3] = (short)f2b(lo1.w);
            a1[4] = (short)f2b(hi1.x); a1[5] = (short)f2b(hi1.y);
            a1[6] = (short)f2b(hi1.z); a1[7] = (short)f2b(hi1.w);
        } else {
            const ushort* Xb = (const ushort*)Xp;
            a0 = *(const bf16x8*)(Xb + (size_t)r0c * K + k0);
            a1 = *(const bf16x8*)(Xb + (size_t)r1c * K + k0);
        }
        #pragma unroll
        for (int n = 0; n < 8; ++n) {
            bf16x8 b = *(const bf16x8*)(Wt + (size_t)(n * 16 + c16) * K + k0);
            acc[0][n] = __builtin_amdgcn_mfma_f32_16x16x32_bf16(a0, b, acc[0][n], 0, 0, 0);
            acc[1][n] = __builtin_amdgcn_mfma_f32_16x16x32_bf16(a1, b, acc[1][n], 0, 0, 0);
        }
    }

    float avs[8], avd[8];
    #pragma unroll
    for (int n = 0; n < 8; ++n) {
        avs[n] = a_src[n * 16 + c16];
        avd[n] = a_dst[n * 16 + c16];
    }

    #pragma unroll
    for (int m = 0; m < 2; ++m) {
        #pragma unroll
        for (int j = 0; j < 4; ++j) {
            const int gr = rowBase + m * 16 + kg * 4 + j;
            const bool ok = (gr < NN);
            if (ok) {
                #pragma unroll
                for (int n = 0; n < 8; ++n)
                    Hf8[(size_t)gr * HD + n * 16 + c16] = f2fp8(acc[m][n][j]);
            }
            float ps = 0.f, pd = 0.f;
            #pragma unroll
            for (int n = 0; n < 8; ++n) {
                ps = fmaf(acc[m][n][j], avs[n], ps);
                pd = fmaf(acc[m][n][j], avd[n], pd);
            }
            #pragma unroll
            for (int off = 8; off >= 1; off >>= 1) {
                ps += __shfl_xor(ps, off);
                pd += __shfl_xor(pd, off);
            }
            if (ok && c16 == 0) { As[gr] = ps; Ad[gr] = pd; }
        }
    }
}

// ---------------- K1: edge partition (4096 edges/blk, per-wave hists) || gemm0 ----------------

__global__ __launch_bounds__(256) void k1_kernel(
        const int* __restrict__ ei, int* __restrict__ cur, uint* __restrict__ stage,
        const float* __restrict__ x, const ushort* __restrict__ Wt0,
        const float* __restrict__ as0, const float* __restrict__ ad0,
        uchar* __restrict__ hf8, float* __restrict__ As, float* __restrict__ Ad) {
    const int vb = blockIdx.x;
    if (vb < EB2) {
        __shared__ int cnt[4][NCB];
        __shared__ int wbase[4][NCB];
        const int t = threadIdx.x;
        const int w = t >> 6;
        for (int i = t; i < 4 * NCB; i += 256) ((int*)cnt)[i] = 0;
        __syncthreads();
        const int base = vb * 4096;
        int src[16], dst[16];
        #pragma unroll
        for (int i = 0; i < 16; ++i) {
            int e = base + t + i * 256;
            if (e < NE) {
                src[i] = ei[e];
                dst[i] = ei[NE + e];
                atomicAdd(&cnt[w][dst[i] >> 10], 1);
            } else dst[i] = -1;
        }
        __syncthreads();
        if (t < NCB) {
            int c0 = cnt[0][t], c1 = cnt[1][t], c2 = cnt[2][t], c3 = cnt[3][t];
            int tot = c0 + c1 + c2 + c3;
            if (tot) {
                int gb = t * CAP + atomicAdd(&cur[t << 4], tot);  // reserve run
                wbase[0][t] = gb;
                wbase[1][t] = gb + c0;
                wbase[2][t] = gb + c0 + c1;
                wbase[3][t] = gb + c0 + c1 + c2;
            }
        }
        __syncthreads();
        if (t < NCB) {            // per-wave cursors (reuse cnt)
            cnt[0][t] = wbase[0][t];
            cnt[1][t] = wbase[1][t];
            cnt[2][t] = wbase[2][t];
            cnt[3][t] = wbase[3][t];
        }
        __syncthreads();
        #pragma unroll
        for (int i = 0; i < 16; ++i) {
            if (dst[i] >= 0) {
                int pos = atomicAdd(&cnt[w][dst[i] >> 10], 1);
                stage[pos] = ((uint)src[i] << 10) | ((uint)dst[i] & 1023u);
            }
        }
    } else {
        gemm_body<64, true>(vb - EB2, x, Wt0, as0, ad0, hf8, As, Ad);
    }
}

template <int K>
__global__ __launch_bounds__(256) void gemm_mfma_kernel(const ushort* __restrict__ Xb,
                                                        const ushort* __restrict__ Wt,
                                                        const float* __restrict__ a_src,
                                                        const float* __restrict__ a_dst,
                                                        uchar* __restrict__ Hf8,
                                                        float* __restrict__ As,
                                                        float* __restrict__ Ad) {
    gemm_body<K, false>(blockIdx.x, Xb, Wt, a_src, a_dst, Hf8, As, Ad);
}

// ---------------- p2 (1024 thr): cursor scan + deg + rowptr + placement ----------------

__global__ __launch_bounds__(1024) void p2_fused_kernel(const uint* __restrict__ stage,
                                                        const int* __restrict__ cur,
                                                        int* __restrict__ rowptr,
                                                        int* __restrict__ col) {
    __shared__ int pre[128];
    __shared__ int d[1024];
    __shared__ int ts[1024];
    const int t = threadIdx.x, b = blockIdx.x;

    // scan the 98 bucket counts (inclusive) -> exclusive base for this bucket
    if (t < 128) pre[t] = (t < NCB) ? cur[t << 4] : 0;
    __syncthreads();
    #pragma unroll
    for (int o = 1; o < 128; o <<= 1) {
        int add = (t < 128 && t >= o) ? pre[t - o] : 0;
        __syncthreads();
        if (t < 128) pre[t] += add;
        __syncthreads();
    }
    const int count = cur[b << 4];
    const int s0 = b * CAP, s1 = s0 + count;
    const int bucketStart = (pre[b] - count) + (b << 10);  // excl edge prefix + self loops

    d[t] = 0;
    __syncthreads();
    for (int i = s0 + t; i < s1; i += 1024) atomicAdd(&d[stage[i] & 1023u], 1);
    __syncthreads();

    const int a = d[t];                        // deg of local node t
    ts[t] = a;
    __syncthreads();
    #pragma unroll
    for (int o = 1; o < 1024; o <<= 1) {       // inclusive block scan
        int add = (t >= o) ? ts[t - o] : 0;
        __syncthreads();
        ts[t] += add;
        __syncthreads();
    }
    const int e0 = bucketStart + (ts[t] - a) + t;  // rowptr (t = local self loops before)
    const int node = (b << 10) + t;
    if (node < NN) {
        rowptr[node] = e0;
        col[e0 + a] = node;                    // self loop -> last slot
    }
    if (b == NCB - 1 && t == 0) rowptr[NN] = ET;
    d[t] = e0;                                 // becomes the placement cursor
    __syncthreads();
    for (int i = s0 + t; i < s1; i += 1024) {
        uint v = stage[i];
        int pos = atomicAdd(&d[v & 1023u], 1);
        col[pos] = (int)(v >> 10);
    }
}

// ---------------- per-dst online softmax + aggregate (EXACT r17 form) ----------------

__global__ __launch_bounds__(256, 8) void aggregate_kernel(const uchar* __restrict__ h8,
                                                           const float* __restrict__ As,
                                                           const float* __restrict__ Ad,
                                                           const int* __restrict__ rowptr,
                                                           const int* __restrict__ col,
                                                           const float* __restrict__ bias,
                                                           ushort* __restrict__ out,
                                                           int relu) {
    __shared__ float wl[8][32];
    __shared__ int   scl[8][32];
    const int lane  = threadIdx.x & 63;
    const int sub   = lane & 31;        // lane within node
    const int g2    = sub >> 4;         // edge-group 0/1
    const int q     = sub & 15;         // feature lane -> feats [q*8, q*8+8)
    const int nslot = ((threadIdx.x >> 6) << 1) + (lane >> 5);  // 0..7
    const int node  = blockIdx.x * 8 + nslot;
    // grid is exact: 12500 * 8 == NN

    const int start = rowptr[node];
    const int end   = rowptr[node + 1];
    const float ad_i = Ad[node];

    float m = -1e30f;
    float denom = 0.f;
    f32x2 acc2[4] = {};

    for (int base = start; base < end; base += 32) {
        const int cnt = min(32, end - base);
        int   sc = 0;
        float e  = -1e30f;
        if (sub < cnt) {
            sc = col[base + sub];
            float a = As[sc] + ad_i;
            e = (a > 0.f) ? a : 0.2f * a;       // leaky_relu 0.2
        }
        float cmax = e;
        #pragma unroll
        for (int off = 16; off >= 1; off >>= 1) cmax = fmaxf(cmax, __shfl_xor(cmax, off));
        float s = __expf(fminf(m - cmax, 0.f));  // branchless online rescale
        m = fmaxf(m, cmax);
        f32x2 s2 = {s, s};
        #pragma unroll
        for (int i = 0; i < 4; ++i) acc2[i] *= s2;
        denom *= s;

        float w = (sub < cnt) ? __expf(e - m) : 0.f;
        denom += w;

        wl[nslot][sub]  = w;     // wave-synchronous stash (w=0, sc=0 for invalid subs)
        scl[nslot][sub] = sc;

        for (int jj = 0; jj < cnt; jj += 8) {
            const int j0 = jj + 4 * g2;          // 16B-aligned within the stash row
            float4 w4 = *(const float4*)&wl[nslot][j0];
            int4   s4 = *(const int4*)&scl[nslot][j0];
            float wv[4] = {w4.x, w4.y, w4.z, w4.w};
            int   sv[4] = {s4.x, s4.y, s4.z, s4.w};
            uint2 vv[4];
            #pragma unroll
            for (int u = 0; u < 4; ++u)
                vv[u] = *(const uint2*)(h8 + (size_t)sv[u] * HD + q * 8);
            #pragma unroll
            for (int u = 0; u < 4; ++u) {
                f32x2 w2 = {wv[u], wv[u]};
                f32x2 p0 = __builtin_amdgcn_cvt_pk_f32_fp8(vv[u].x, false);
                f32x2 p1 = __builtin_amdgcn_cvt_pk_f32_fp8(vv[u].x, true);
                f32x2 p2 = __builtin_amdgcn_cvt_pk_f32_fp8(vv[u].y, false);
                f32x2 p3 = __builtin_amdgcn_cvt_pk_f32_fp8(vv[u].y, true);
                acc2[0] = __builtin_elementwise_fma(w2, p0, acc2[0]);
                acc2[1] = __builtin_elementwise_fma(w2, p1, acc2[1]);
                acc2[2] = __builtin_elementwise_fma(w2, p2, acc2[2]);
                acc2[3] = __builtin_elementwise_fma(w2, p3, acc2[3]);
            }
        }
    }

    float accf[8];
    #pragma unroll
    for (int i = 0; i < 4; ++i) { accf[2 * i] = acc2[i][0]; accf[2 * i + 1] = acc2[i][1]; }

    // cross-group feature reduce (xor 16 combines the node's two groups)
    #pragma unroll
    for (int i = 0; i < 8; ++i) accf[i] += __shfl_xor(accf[i], 16);
    #pragma unroll
    for (int off = 16; off >= 1; off >>= 1) denom += __shfl_xor(denom, off);

    if (g2 == 0) {
        float inv = 1.0f / denom;
        float4 bv0 = *(const float4*)&bias[q * 8];
        float4 bv1 = *(const float4*)&bias[q * 8 + 4];
        float bb[8] = {bv0.x, bv0.y, bv0.z, bv0.w, bv1.x, bv1.y, bv1.z, bv1.w};
        u16x8 o;
        #pragma unroll
        for (int i = 0; i < 8; ++i) {
            float v = fmaf(accf[i], inv, bb[i]);
            if (relu) v = fmaxf(v, 0.f);
            o[i] = f2b(v);
        }
        *(u16x8*)&out[(size_t)node * HD + q * 8] = o;
    }
}

// ---------------- readout: vectorized graph sum + finalize (ticket fused) ----------------
// Wave covers 4 rows/iter (lane = u16x8, 16B). Lane l accumulates feats (l&15)*8..+8
// of row group l>>4; fold groups via shfl_xor(16,32); LDS block-reduce; slot atomics.

__global__ __launch_bounds__(256) void sum_finalize_kernel(
        const ushort* __restrict__ h, float* __restrict__ g, int* __restrict__ done,
        const float* __restrict__ Wp, const float* __restrict__ bp,
        float* __restrict__ out) {
    const int t = threadIdx.x;
    const int wave = t >> 6, lane = t & 63;
    const int q = lane & 15;
    float acc[8] = {};
    const int wg = blockIdx.x * 4 + wave;          // global wave id (8192 total)
    for (int rb = wg * 4; rb < NN; rb += SB * 4 * 4) {   // 4 rows per iteration
        u16x8 v = *(const u16x8*)&h[(size_t)rb * HD + lane * 8];
        #pragma unroll
        for (int i = 0; i < 8; ++i) acc[i] += b2f(v[i]);
    }
    #pragma unroll
    for (int i = 0; i < 8; ++i) {
        acc[i] += __shfl_xor(acc[i], 16);
        acc[i] += __shfl_xor(acc[i], 32);
    }
    __shared__ float sm[512];
    __shared__ int lastBlk;
    if (lane < 16) {
        #pragma unroll
        for (int i = 0; i < 8; ++i) sm[wave * 128 + q * 8 + i] = acc[i];
    }
    __syncthreads();
    if (t < 128) {
        float s = sm[t] + sm[128 + t] + sm[256 + t] + sm[384 + t];
        atomicAdd(&g[(blockIdx.x & (NSLOT - 1)) * 128 + t], s);
    }
    __threadfence();                 // make this block's g-adds visible device-wide
    __syncthreads();
    if (t == 0) lastBlk = (atomicAdd(done, 1) == (int)gridDim.x - 1) ? 1 : 0;
    __syncthreads();
    if (lastBlk) {
        __shared__ float red[2];
        if (t < 128) {
            float s = 0.f;
            for (int r = 0; r < NSLOT; ++r) s += atomicAdd(&g[r * 128 + t], 0.f);
            float v = s * (1.0f / NN) * Wp[t];
            #pragma unroll
            for (int mm = 32; mm >= 1; mm >>= 1) v += __shfl_xor(v, mm);
            if ((t & 63) == 0) red[t >> 6] = v;
        }
        __syncthreads();
        if (t == 0) out[0] = red[0] + red[1] + bp[0];
    }
}

// ---------------- launch ----------------

extern "C" void kernel_launch(void* const* d_in, const int* in_sizes, int n_in,
                              void* d_out, int out_size, void* d_ws, size_t ws_size,
                              hipStream_t stream) {
    const float* x   = (const float*)d_in[0];
    const int*   ei  = (const int*)d_in[1];
    const float* W0  = (const float*)d_in[2];
    const float* W1  = (const float*)d_in[3];
    const float* W2  = (const float*)d_in[4];
    const float* as0 = (const float*)d_in[5];
    const float* as1 = (const float*)d_in[6];
    const float* as2 = (const float*)d_in[7];
    const float* ad0 = (const float*)d_in[8];
    const float* ad1 = (const float*)d_in[9];
    const float* ad2 = (const float*)d_in[10];
    const float* b0  = (const float*)d_in[11];
    const float* b1  = (const float*)d_in[12];
    const float* b2  = (const float*)d_in[13];
    const float* Wp  = (const float*)d_in[14];
    const float* bp  = (const float*)d_in[15];
    float* out = (float*)d_out;

    char* p = (char*)d_ws;
    auto alloc = [&](size_t bytes) {
        char* r = p;
        p += (bytes + 255) & ~(size_t)255;
        return r;
    };
    uchar*  hf8    = (uchar*)alloc((size_t)NN * HD);        // fp8 gather rows
    ushort* abf    = (ushort*)alloc((size_t)NN * HD * 2);   // aggregate output (bf16)
    ushort* Wt0    = (ushort*)alloc((size_t)64 * 128 * 2);  // transposed bf16 weights
    ushort* Wt1    = (ushort*)alloc((size_t)128 * 128 * 2);
    ushort* Wt2    = (ushort*)alloc((size_t)128 * 128 * 2);
    float* As      = (float*)alloc((size_t)NN * 4);
    float* Ad      = (float*)alloc((size_t)NN * 4);
    int*   rowptr  = (int*)alloc((size_t)(NN + 1) * 4);
    uint*  stage   = (uint*)alloc((size_t)NCB * CAP * 4);   // fixed-cap buckets
    int*   col     = (int*)alloc((size_t)ET * 4);
    int*   cur     = (int*)alloc((size_t)NCB * 16 * 4);     // padded cursors
    float* g       = (float*)alloc((size_t)NSLOT * 128 * 4);
    int*   done    = (int*)alloc(256);

    // setup: zero cur/g/done + W->Wt converts (64 blocks cover 16384 elements)
    setup_kernel<<<64, 256, 0, stream>>>(W0, W1, W2, Wt0, Wt1, Wt2, cur, g, done);

    // K1: edge partition || layer-0 gemm (x fp32 in-reg convert, Wt0 from global)
    k1_kernel<<<EB2 + GB, 256, 0, stream>>>(ei, cur, stage, x, Wt0, as0, ad0,
                                            hf8, As, Ad);
    // p2: cursor scan + deg + rowptr + self loops + placement
    p2_fused_kernel<<<NCB, 1024, 0, stream>>>(stage, cur, rowptr, col);

    const int AB = NN / 8;  // 12500 (exact)

    // layer 0 aggregate
    aggregate_kernel<<<AB, 256, 0, stream>>>(hf8, As, Ad, rowptr, col, b0, abf, 1);
    // layer 1
    gemm_mfma_kernel<128><<<GB, 256, 0, stream>>>(abf, Wt1, as1, ad1, hf8, As, Ad);
    aggregate_kernel<<<AB, 256, 0, stream>>>(hf8, As, Ad, rowptr, col, b1, abf, 1);
    // layer 2
    gemm_mfma_kernel<128><<<GB, 256, 0, stream>>>(abf, Wt2, as2, ad2, hf8, As, Ad);
    aggregate_kernel<<<AB, 256, 0, stream>>>(hf8, As, Ad, rowptr, col, b2, abf, 0);

    // readout (vectorized sum + finalize fused)
    sum_finalize_kernel<<<SB, 256, 0, stream>>>(abf, g, done, Wp, bp, out);
}

// Round 21
// 242.449 us; speedup vs baseline: 1.4948x; 1.4948x over previous
//
#include <hip/hip_runtime.h>

// GAT 3-layer, N=100000 nodes, E=1.6M edges (+N self loops), Fin=64, H=128.
// 10-dispatch pipeline:
//   setup{zero cur,g + convert W->Wt} -> K1{edge partition || gemm0}
//   -> p2{CSR build, 1024 thr} -> agg0 -> gemm1 -> agg1 -> gemm2 -> agg2
//   -> sum{vectorized, 2048 blocks, 64-slot} -> finalize{1 block}.
// r21: UNFUSED readout. r20's ticket+__threadfence from 2048 blocks cost 131us
// (device-scope fence = L2 writeback ops, serialized across XCDs). Kernel boundary
// gives visibility for free. Sum keeps the vectorized u16x8 body.
// Aggregate stays EXACT r17 form (r18's guard caused scratch spills — branchless!).

#define NN 100000
#define NE 1600000
#define ET (NE + NN)   // edges + self loops
#define HD 128
#define NCB 98         // coarse buckets = ceil(NN / 1024)
#define CAP 18432      // bucket capacity (mean 16327, +16 sigma)
#define EB2 391        // edge-partition blocks = ceil(NE / 4096)
#define GB 782         // gemm blocks = ceil(NN / 128)
#define SB 2048        // sum blocks (8 per CU)
#define NSLOT 64       // replicated readout accumulator slots

typedef unsigned int uint;
typedef unsigned short ushort;
typedef unsigned char uchar;
typedef __attribute__((ext_vector_type(8))) short bf16x8;
typedef __attribute__((ext_vector_type(8))) ushort u16x8;
typedef __attribute__((ext_vector_type(4))) float f32x4;
typedef __attribute__((ext_vector_type(2))) float f32x2;

__device__ __forceinline__ ushort f2b(float f) {   // fp32 -> bf16 RTN-even
    uint u = __float_as_uint(f);
    return (ushort)((u + 0x7fffu + ((u >> 16) & 1u)) >> 16);
}
__device__ __forceinline__ float b2f(ushort v) { return __uint_as_float((uint)v << 16); }
__device__ __forceinline__ uchar f2fp8(float f) {  // fp32 -> fp8 e4m3 (OCP), RNE+sat
    return (uchar)(__builtin_amdgcn_cvt_pk_fp8_f32(f, f, 0, false) & 0xff);
}

// ---------------- setup: zero cur/g + convert W0/W1/W2 -> transposed bf16 Wt ----------------

__global__ __launch_bounds__(256) void setup_kernel(
        const float* __restrict__ W0, const float* __restrict__ W1,
        const float* __restrict__ W2, ushort* __restrict__ Wt0,
        ushort* __restrict__ Wt1, ushort* __restrict__ Wt2,
        int* __restrict__ cur, float* __restrict__ g) {
    const int i = blockIdx.x * 256 + threadIdx.x;   // 64 blocks -> i < 16384
    if (i < NCB * 16) cur[i] = 0;
    if (i < NSLOT * 128) g[i] = 0.f;
    if (i < 128 * 64) {                 // Wt0[n*64+k] = bf16(W0[k*128+n])
        int n = i >> 6, k = i & 63;
        Wt0[i] = f2b(W0[k * 128 + n]);
    }
    {                                   // Wt1/Wt2: i covers 128*128 exactly
        int n = i >> 7, k = i & 127;
        Wt1[i] = f2b(W1[k * 128 + n]);
        Wt2[i] = f2b(W2[k * 128 + n]);
    }
}

// ---------------- MFMA GEMM body: Hf8 = fp8(X @ W), fused fp32 alpha epilogue ----------------

template <int K, bool XF32>
__device__ __forceinline__ void gemm_body(int bid, const void* Xp,
                                          const ushort* __restrict__ Wt,
                                          const float* __restrict__ a_src,
                                          const float* __restrict__ a_dst,
                                          uchar* __restrict__ Hf8,
                                          float* __restrict__ As,
                                          float* __restrict__ Ad) {
    const int t = threadIdx.x;
    const int w = t >> 6;
    const int l = t & 63;
    const int c16 = l & 15;
    const int kg = l >> 4;
    const int rowBase = bid * 128 + w * 32;

    f32x4 acc[2][8] = {};

    const int r0c = min(rowBase + c16, NN - 1);
    const int r1c = min(rowBase + 16 + c16, NN - 1);

    #pragma unroll
    for (int ks = 0; ks < K / 32; ++ks) {
        const int k0 = ks * 32 + kg * 8;
        bf16x8 a0, a1;
        if (XF32) {
            const float* Xf = (const float*)Xp;
            float4 lo0 = *(const float4*)&Xf[(size_t)r0c * K + k0];
            float4 hi0 = *(const float4*)&Xf[(size_t)r0c * K + k0 + 4];
            float4 lo1 = *(const float4*)&Xf[(size_t)r1c * K + k0];
            float4 hi1 = *(const float4*)&Xf[(size_t)r1c * K + k0 + 4];
            a0[0] = (short)f2b(lo0.x); a0[1] = (short)f2b(lo0.y);
            a0[2] = (short)f2b(lo0.z); a0[3] = (short)f2b(lo0.w);
            a0[4] = (short)f2b(hi0.x); a0[5] = (short)f2b(hi0.y);
            a0[6] = (short)f2b(hi0.z); a0[7] = (short)f2b(hi0.w);
            a1[0] = (short)f2b(lo1.x); a1[1] = (short)f2b(lo1.y);
            a1[2] = (short)f2b(lo1.z); a1[3] = (short)f2b(lo1.w);
            a1[4] = (short)f2b(hi1.x); a1[5] = (short)f2b(hi1.y);
            a1[6] = (short)f2b(hi1.z); a1[7] = (short)f2b(hi1.w);
        } else {
            const ushort* Xb = (const ushort*)Xp;
            a0 = *(const bf16x8*)(Xb + (size_t)r0c * K + k0);
            a1 = *(const bf16x8*)(Xb + (size_t)r1c * K + k0);
        }
        #pragma unroll
        for (int n = 0; n < 8; ++n) {
            bf16x8 b = *(const bf16x8*)(Wt + (size_t)(n * 16 + c16) * K + k0);
            acc[0][n] = __builtin_amdgcn_mfma_f32_16x16x32_bf16(a0, b, acc[0][n], 0, 0, 0);
            acc[1][n] = __builtin_amdgcn_mfma_f32_16x16x32_bf16(a1, b, acc[1][n], 0, 0, 0);
        }
    }

    float avs[8], avd[8];
    #pragma unroll
    for (int n = 0; n < 8; ++n) {
        avs[n] = a_src[n * 16 + c16];
        avd[n] = a_dst[n * 16 + c16];
    }

    #pragma unroll
    for (int m = 0; m < 2; ++m) {
        #pragma unroll
        for (int j = 0; j < 4; ++j) {
            const int gr = rowBase + m * 16 + kg * 4 + j;
            const bool ok = (gr < NN);
            if (ok) {
                #pragma unroll
                for (int n = 0; n < 8; ++n)
                    Hf8[(size_t)gr * HD + n * 16 + c16] = f2fp8(acc[m][n][j]);
            }
            float ps = 0.f, pd = 0.f;
            #pragma unroll
            for (int n = 0; n < 8; ++n) {
                ps = fmaf(acc[m][n][j], avs[n], ps);
                pd = fmaf(acc[m][n][j], avd[n], pd);
            }
            #pragma unroll
            for (int off = 8; off >= 1; off >>= 1) {
                ps += __shfl_xor(ps, off);
                pd += __shfl_xor(pd, off);
            }
            if (ok && c16 == 0) { As[gr] = ps; Ad[gr] = pd; }
        }
    }
}

// ---------------- K1: edge partition (4096 edges/blk, per-wave hists) || gemm0 ----------------

__global__ __launch_bounds__(256) void k1_kernel(
        const int* __restrict__ ei, int* __restrict__ cur, uint* __restrict__ stage,
        const float* __restrict__ x, const ushort* __restrict__ Wt0,
        const float* __restrict__ as0, const float* __restrict__ ad0,
        uchar* __restrict__ hf8, float* __restrict__ As, float* __restrict__ Ad) {
    const int vb = blockIdx.x;
    if (vb < EB2) {
        __shared__ int cnt[4][NCB];
        __shared__ int wbase[4][NCB];
        const int t = threadIdx.x;
        const int w = t >> 6;
        for (int i = t; i < 4 * NCB; i += 256) ((int*)cnt)[i] = 0;
        __syncthreads();
        const int base = vb * 4096;
        int src[16], dst[16];
        #pragma unroll
        for (int i = 0; i < 16; ++i) {
            int e = base + t + i * 256;
            if (e < NE) {
                src[i] = ei[e];
                dst[i] = ei[NE + e];
                atomicAdd(&cnt[w][dst[i] >> 10], 1);
            } else dst[i] = -1;
        }
        __syncthreads();
        if (t < NCB) {
            int c0 = cnt[0][t], c1 = cnt[1][t], c2 = cnt[2][t], c3 = cnt[3][t];
            int tot = c0 + c1 + c2 + c3;
            if (tot) {
                int gb = t * CAP + atomicAdd(&cur[t << 4], tot);  // reserve run
                wbase[0][t] = gb;
                wbase[1][t] = gb + c0;
                wbase[2][t] = gb + c0 + c1;
                wbase[3][t] = gb + c0 + c1 + c2;
            }
        }
        __syncthreads();
        if (t < NCB) {            // per-wave cursors (reuse cnt)
            cnt[0][t] = wbase[0][t];
            cnt[1][t] = wbase[1][t];
            cnt[2][t] = wbase[2][t];
            cnt[3][t] = wbase[3][t];
        }
        __syncthreads();
        #pragma unroll
        for (int i = 0; i < 16; ++i) {
            if (dst[i] >= 0) {
                int pos = atomicAdd(&cnt[w][dst[i] >> 10], 1);
                stage[pos] = ((uint)src[i] << 10) | ((uint)dst[i] & 1023u);
            }
        }
    } else {
        gemm_body<64, true>(vb - EB2, x, Wt0, as0, ad0, hf8, As, Ad);
    }
}

template <int K>
__global__ __launch_bounds__(256) void gemm_mfma_kernel(const ushort* __restrict__ Xb,
                                                        const ushort* __restrict__ Wt,
                                                        const float* __restrict__ a_src,
                                                        const float* __restrict__ a_dst,
                                                        uchar* __restrict__ Hf8,
                                                        float* __restrict__ As,
                                                        float* __restrict__ Ad) {
    gemm_body<K, false>(blockIdx.x, Xb, Wt, a_src, a_dst, Hf8, As, Ad);
}

// ---------------- p2 (1024 thr): cursor scan + deg + rowptr + placement ----------------

__global__ __launch_bounds__(1024) void p2_fused_kernel(const uint* __restrict__ stage,
                                                        const int* __restrict__ cur,
                                                        int* __restrict__ rowptr,
                                                        int* __restrict__ col) {
    __shared__ int pre[128];
    __shared__ int d[1024];
    __shared__ int ts[1024];
    const int t = threadIdx.x, b = blockIdx.x;

    // scan the 98 bucket counts (inclusive) -> exclusive base for this bucket
    if (t < 128) pre[t] = (t < NCB) ? cur[t << 4] : 0;
    __syncthreads();
    #pragma unroll
    for (int o = 1; o < 128; o <<= 1) {
        int add = (t < 128 && t >= o) ? pre[t - o] : 0;
        __syncthreads();
        if (t < 128) pre[t] += add;
        __syncthreads();
    }
    const int count = cur[b << 4];
    const int s0 = b * CAP, s1 = s0 + count;
    const int bucketStart = (pre[b] - count) + (b << 10);  // excl edge prefix + self loops

    d[t] = 0;
    __syncthreads();
    for (int i = s0 + t; i < s1; i += 1024) atomicAdd(&d[stage[i] & 1023u], 1);
    __syncthreads();

    const int a = d[t];                        // deg of local node t
    ts[t] = a;
    __syncthreads();
    #pragma unroll
    for (int o = 1; o < 1024; o <<= 1) {       // inclusive block scan
        int add = (t >= o) ? ts[t - o] : 0;
        __syncthreads();
        ts[t] += add;
        __syncthreads();
    }
    const int e0 = bucketStart + (ts[t] - a) + t;  // rowptr (t = local self loops before)
    const int node = (b << 10) + t;
    if (node < NN) {
        rowptr[node] = e0;
        col[e0 + a] = node;                    // self loop -> last slot
    }
    if (b == NCB - 1 && t == 0) rowptr[NN] = ET;
    d[t] = e0;                                 // becomes the placement cursor
    __syncthreads();
    for (int i = s0 + t; i < s1; i += 1024) {
        uint v = stage[i];
        int pos = atomicAdd(&d[v & 1023u], 1);
        col[pos] = (int)(v >> 10);
    }
}

// ---------------- per-dst online softmax + aggregate (EXACT r17 form) ----------------

__global__ __launch_bounds__(256, 8) void aggregate_kernel(const uchar* __restrict__ h8,
                                                           const float* __restrict__ As,
                                                           const float* __restrict__ Ad,
                                                           const int* __restrict__ rowptr,
                                                           const int* __restrict__ col,
                                                           const float* __restrict__ bias,
                                                           ushort* __restrict__ out,
                                                           int relu) {
    __shared__ float wl[8][32];
    __shared__ int   scl[8][32];
    const int lane  = threadIdx.x & 63;
    const int sub   = lane & 31;        // lane within node
    const int g2    = sub >> 4;         // edge-group 0/1
    const int q     = sub & 15;         // feature lane -> feats [q*8, q*8+8)
    const int nslot = ((threadIdx.x >> 6) << 1) + (lane >> 5);  // 0..7
    const int node  = blockIdx.x * 8 + nslot;
    // grid is exact: 12500 * 8 == NN

    const int start = rowptr[node];
    const int end   = rowptr[node + 1];
    const float ad_i = Ad[node];

    float m = -1e30f;
    float denom = 0.f;
    f32x2 acc2[4] = {};

    for (int base = start; base < end; base += 32) {
        const int cnt = min(32, end - base);
        int   sc = 0;
        float e  = -1e30f;
        if (sub < cnt) {
            sc = col[base + sub];
            float a = As[sc] + ad_i;
            e = (a > 0.f) ? a : 0.2f * a;       // leaky_relu 0.2
        }
        float cmax = e;
        #pragma unroll
        for (int off = 16; off >= 1; off >>= 1) cmax = fmaxf(cmax, __shfl_xor(cmax, off));
        float s = __expf(fminf(m - cmax, 0.f));  // branchless online rescale
        m = fmaxf(m, cmax);
        f32x2 s2 = {s, s};
        #pragma unroll
        for (int i = 0; i < 4; ++i) acc2[i] *= s2;
        denom *= s;

        float w = (sub < cnt) ? __expf(e - m) : 0.f;
        denom += w;

        wl[nslot][sub]  = w;     // wave-synchronous stash (w=0, sc=0 for invalid subs)
        scl[nslot][sub] = sc;

        for (int jj = 0; jj < cnt; jj += 8) {
            const int j0 = jj + 4 * g2;          // 16B-aligned within the stash row
            float4 w4 = *(const float4*)&wl[nslot][j0];
            int4   s4 = *(const int4*)&scl[nslot][j0];
            float wv[4] = {w4.x, w4.y, w4.z, w4.w};
            int   sv[4] = {s4.x, s4.y, s4.z, s4.w};
            uint2 vv[4];
            #pragma unroll
            for (int u = 0; u < 4; ++u)
                vv[u] = *(const uint2*)(h8 + (size_t)sv[u] * HD + q * 8);
            #pragma unroll
            for (int u = 0; u < 4; ++u) {
                f32x2 w2 = {wv[u], wv[u]};
                f32x2 p0 = __builtin_amdgcn_cvt_pk_f32_fp8(vv[u].x, false);
                f32x2 p1 = __builtin_amdgcn_cvt_pk_f32_fp8(vv[u].x, true);
                f32x2 p2 = __builtin_amdgcn_cvt_pk_f32_fp8(vv[u].y, false);
                f32x2 p3 = __builtin_amdgcn_cvt_pk_f32_fp8(vv[u].y, true);
                acc2[0] = __builtin_elementwise_fma(w2, p0, acc2[0]);
                acc2[1] = __builtin_elementwise_fma(w2, p1, acc2[1]);
                acc2[2] = __builtin_elementwise_fma(w2, p2, acc2[2]);
                acc2[3] = __builtin_elementwise_fma(w2, p3, acc2[3]);
            }
        }
    }

    float accf[8];
    #pragma unroll
    for (int i = 0; i < 4; ++i) { accf[2 * i] = acc2[i][0]; accf[2 * i + 1] = acc2[i][1]; }

    // cross-group feature reduce (xor 16 combines the node's two groups)
    #pragma unroll
    for (int i = 0; i < 8; ++i) accf[i] += __shfl_xor(accf[i], 16);
    #pragma unroll
    for (int off = 16; off >= 1; off >>= 1) denom += __shfl_xor(denom, off);

    if (g2 == 0) {
        float inv = 1.0f / denom;
        float4 bv0 = *(const float4*)&bias[q * 8];
        float4 bv1 = *(const float4*)&bias[q * 8 + 4];
        float bb[8] = {bv0.x, bv0.y, bv0.z, bv0.w, bv1.x, bv1.y, bv1.z, bv1.w};
        u16x8 o;
        #pragma unroll
        for (int i = 0; i < 8; ++i) {
            float v = fmaf(accf[i], inv, bb[i]);
            if (relu) v = fmaxf(v, 0.f);
            o[i] = f2b(v);
        }
        *(u16x8*)&out[(size_t)node * HD + q * 8] = o;
    }
}

// ---------------- readout: vectorized graph sum -> 64 replicated slots ----------------
// Wave covers 4 rows/iter (lane = u16x8, 16B). Fold via shfl_xor(16,32), LDS block
// reduce, one atomicAdd per thread into slot (blockIdx & 63). No fence/ticket.

__global__ __launch_bounds__(256) void sum_kernel(const ushort* __restrict__ h,
                                                  float* __restrict__ g) {
    const int t = threadIdx.x;
    const int wave = t >> 6, lane = t & 63;
    const int q = lane & 15;
    float acc[8] = {};
    const int wg = blockIdx.x * 4 + wave;          // global wave id (8192 total)
    for (int rb = wg * 4; rb < NN; rb += SB * 4 * 4) {   // 4 rows per iteration
        u16x8 v = *(const u16x8*)&h[(size_t)rb * HD + lane * 8];
        #pragma unroll
        for (int i = 0; i < 8; ++i) acc[i] += b2f(v[i]);
    }
    #pragma unroll
    for (int i = 0; i < 8; ++i) {
        acc[i] += __shfl_xor(acc[i], 16);
        acc[i] += __shfl_xor(acc[i], 32);
    }
    __shared__ float sm[512];
    if (lane < 16) {
        #pragma unroll
        for (int i = 0; i < 8; ++i) sm[wave * 128 + q * 8 + i] = acc[i];
    }
    __syncthreads();
    if (t < 128) {
        float s = sm[t] + sm[128 + t] + sm[256 + t] + sm[384 + t];
        atomicAdd(&g[(blockIdx.x & (NSLOT - 1)) * 128 + t], s);
    }
}

// ---------------- finalize: out = (sum_slots(g)/NN) @ Wp + bp ----------------

__global__ void finalize_kernel(const float* __restrict__ g, const float* __restrict__ Wp,
                                const float* __restrict__ bp, float* __restrict__ out) {
    int t = threadIdx.x;
    float s = 0.f;
    for (int r = 0; r < NSLOT; ++r) s += g[r * 128 + t];
    float v = s * (1.0f / NN) * Wp[t];
    #pragma unroll
    for (int m = 32; m >= 1; m >>= 1) v += __shfl_xor(v, m);
    __shared__ float red[2];
    if ((t & 63) == 0) red[t >> 6] = v;
    __syncthreads();
    if (t == 0) out[0] = red[0] + red[1] + bp[0];
}

// ---------------- launch ----------------

extern "C" void kernel_launch(void* const* d_in, const int* in_sizes, int n_in,
                              void* d_out, int out_size, void* d_ws, size_t ws_size,
                              hipStream_t stream) {
    const float* x   = (const float*)d_in[0];
    const int*   ei  = (const int*)d_in[1];
    const float* W0  = (const float*)d_in[2];
    const float* W1  = (const float*)d_in[3];
    const float* W2  = (const float*)d_in[4];
    const float* as0 = (const float*)d_in[5];
    const float* as1 = (const float*)d_in[6];
    const float* as2 = (const float*)d_in[7];
    const float* ad0 = (const float*)d_in[8];
    const float* ad1 = (const float*)d_in[9];
    const float* ad2 = (const float*)d_in[10];
    const float* b0  = (const float*)d_in[11];
    const float* b1  = (const float*)d_in[12];
    const float* b2  = (const float*)d_in[13];
    const float* Wp  = (const float*)d_in[14];
    const float* bp  = (const float*)d_in[15];
    float* out = (float*)d_out;

    char* p = (char*)d_ws;
    auto alloc = [&](size_t bytes) {
        char* r = p;
        p += (bytes + 255) & ~(size_t)255;
        return r;
    };
    uchar*  hf8    = (uchar*)alloc((size_t)NN * HD);        // fp8 gather rows
    ushort* abf    = (ushort*)alloc((size_t)NN * HD * 2);   // aggregate output (bf16)
    ushort* Wt0    = (ushort*)alloc((size_t)64 * 128 * 2);  // transposed bf16 weights
    ushort* Wt1    = (ushort*)alloc((size_t)128 * 128 * 2);
    ushort* Wt2    = (ushort*)alloc((size_t)128 * 128 * 2);
    float* As      = (float*)alloc((size_t)NN * 4);
    float* Ad      = (float*)alloc((size_t)NN * 4);
    int*   rowptr  = (int*)alloc((size_t)(NN + 1) * 4);
    uint*  stage   = (uint*)alloc((size_t)NCB * CAP * 4);   // fixed-cap buckets
    int*   col     = (int*)alloc((size_t)ET * 4);
    int*   cur     = (int*)alloc((size_t)NCB * 16 * 4);     // padded cursors
    float* g       = (float*)alloc((size_t)NSLOT * 128 * 4);

    // setup: zero cur/g + W->Wt converts (64 blocks cover 16384 elements)
    setup_kernel<<<64, 256, 0, stream>>>(W0, W1, W2, Wt0, Wt1, Wt2, cur, g);

    // K1: edge partition || layer-0 gemm (x fp32 in-reg convert, Wt0 from global)
    k1_kernel<<<EB2 + GB, 256, 0, stream>>>(ei, cur, stage, x, Wt0, as0, ad0,
                                            hf8, As, Ad);
    // p2: cursor scan + deg + rowptr + self loops + placement
    p2_fused_kernel<<<NCB, 1024, 0, stream>>>(stage, cur, rowptr, col);

    const int AB = NN / 8;  // 12500 (exact)

    // layer 0 aggregate
    aggregate_kernel<<<AB, 256, 0, stream>>>(hf8, As, Ad, rowptr, col, b0, abf, 1);
    // layer 1
    gemm_mfma_kernel<128><<<GB, 256, 0, stream>>>(abf, Wt1, as1, ad1, hf8, As, Ad);
    aggregate_kernel<<<AB, 256, 0, stream>>>(hf8, As, Ad, rowptr, col, b1, abf, 1);
    // layer 2
    gemm_mfma_kernel<128><<<GB, 256, 0, stream>>>(abf, Wt2, as2, ad2, hf8, As, Ad);
    aggregate_kernel<<<AB, 256, 0, stream>>>(hf8, As, Ad, rowptr, col, b2, abf, 0);

    // readout: vectorized sum -> slots, then tiny finalize
    sum_kernel<<<SB, 256, 0, stream>>>(abf, g);
    finalize_kernel<<<1, 128, 0, stream>>>(g, Wp, bp, out);
}